// Round 7
// baseline (408.339 us; speedup 1.0000x reference)
//
#include <hip/hip_runtime.h>

#define N_NODES 100000
#define N_EDGES 1600000
#define NPART   8
#define PART_SZ (N_NODES / NPART)   // 12500 (agg node mapping)
#define CAP 48                      // bucket capacity; degree ~ Poisson(16), P(>=48) ~ 1e-9
#define BSH  10                     // nodes per fill bin = 1024 (node-exclusive block ownership)
#define NBIN 98                     // ceil(100000 / 1024)
#define SCAP2 4096                  // per-(bin,stripe) staging cap: mean 2048, sigma 45 -> +45 sigma
#define SSH2 12                     // log2(SCAP2)
#define EPB  2048                   // edges per build block
#define KD4  6                      // gather pipeline depth, agg_h4 (nit <= 6)
#define KD1  3                      // gather pipeline depth, agg_h1 (nit <= 3)

static __device__ __forceinline__ float lrelu(float z) { return z > 0.f ? z : 0.2f * z; }

// bf16 round-to-nearest-even pack / unpack (values are finite, no NaN handling)
static __device__ __forceinline__ unsigned f2bf(float f) {
    unsigned u = __float_as_uint(f);
    u += 0x7fffu + ((u >> 16) & 1u);
    return u >> 16;
}
static __device__ __forceinline__ float bf_lo(unsigned v) { return __uint_as_float(v << 16); }
static __device__ __forceinline__ float bf_hi(unsigned v) { return __uint_as_float(v & 0xffff0000u); }

// ---------------- phase A: single-pass edge binning at 1024-node granularity ----------------
// (round-15: validated — bucket phase now ~25 us total, fill write-amp gone)
__global__ __launch_bounds__(256) void bucket_build(const int* __restrict__ ei, int* __restrict__ tails,
                                                    unsigned* __restrict__ stage) {
    __shared__ int lcnt[NBIN];
    __shared__ int lbase[NBIN];
    int tid = threadIdx.x;
    if (tid < NBIN) lcnt[tid] = 0;
    __syncthreads();

    int stripe = blockIdx.x & 7;
    int e0 = blockIdx.x * EPB;
    int binv[EPB / 256];
    int slotv[EPB / 256];
    unsigned vv[EPB / 256];
#pragma unroll
    for (int k = 0; k < EPB / 256; ++k) {
        int t = e0 + k * 256 + tid;
        binv[k] = -1;
        if (t < N_EDGES) {
            int d = __builtin_nontemporal_load(ei + N_EDGES + t);
            int s = __builtin_nontemporal_load(ei + t);
            int b = d >> BSH;
            vv[k] = ((unsigned)(d & ((1 << BSH) - 1)) << 17) | (unsigned)s;  // dloc 10b | src 17b
            slotv[k] = atomicAdd(&lcnt[b], 1);
            binv[k] = b;
        }
    }
    __syncthreads();

    if (tid < NBIN) lbase[tid] = atomicAdd(&tails[stripe * 128 + tid], lcnt[tid]);
    __syncthreads();

#pragma unroll
    for (int k = 0; k < EPB / 256; ++k) {
        if (binv[k] >= 0) {
            int pos = lbase[binv[k]] + slotv[k];
            if (pos < SCAP2)
                stage[((((unsigned)binv[k] << 3) | (unsigned)stripe) << SSH2) + (unsigned)pos] = vv[k];
        }
    }
}

// ---------------- phase B: node-exclusive bucket assembly, LDS counters only ----------------
__global__ __launch_bounds__(1024) void bucket_fill(const int* __restrict__ tails, const unsigned* __restrict__ stage,
                                                    int* __restrict__ cnt, int* __restrict__ srcs) {
    __shared__ int lc[1 << BSH];
    int tid = threadIdx.x;
    int bin = blockIdx.x;
    int base = bin << BSH;
    int nn = N_NODES - base; if (nn > (1 << BSH)) nn = 1 << BSH;
    if (tid < nn) {
        lc[tid] = 1;                           // self-loop occupies slot 0
        srcs[(base + tid) * CAP] = base + tid;
    }
    __syncthreads();

    for (int st = 0; st < 8; ++st) {
        int len = tails[st * 128 + bin];
        if (len > SCAP2) len = SCAP2;
        const unsigned* sl = stage + ((((unsigned)bin << 3) | (unsigned)st) << SSH2);
        for (int i = tid; i < len; i += 1024) {
            unsigned v = __builtin_nontemporal_load(sl + i);
            int dloc = (int)(v >> 17);
            int s = (int)(v & 0x1FFFFu);
            int slot = atomicAdd(&lc[dloc], 1);
            if (slot < CAP) srcs[(base + dloc) * CAP + slot] = s;
        }
    }
    __syncthreads();
    if (tid < nn) cnt[base + tid] = lc[tid];   // agg clamps deg > CAP
}

// ---------------- fused GEMM + attention logits (wave-sliced, scalar W path) ----------------
template <int IN, int OUT, int HEADS, int NPB>
__global__ __launch_bounds__(256) void gemm_al(const float* __restrict__ x, const float* __restrict__ W,
                                               const float* __restrict__ asrc, const float* __restrict__ adst,
                                               unsigned short* __restrict__ h, float* __restrict__ als,
                                               float* __restrict__ ald) {
    constexpr int SPLIT = OUT / 16;
    constexpr int STRIDE = IN + 1;
    constexpr int F4PT = NPB * (IN / 4) / 256;
    __shared__ float sx[NPB * STRIDE];
    int t = threadIdx.x;
    long base = (long)blockIdx.x * NPB;

#pragma unroll
    for (int p = 0; p < F4PT; ++p) {
        int e = p * 256 + t;
        int row = e / (IN / 4);
        int c4 = e % (IN / 4);
        long gr = base + row;
        if (gr >= N_NODES) gr = N_NODES - 1;
        float4 v = *reinterpret_cast<const float4*>(&x[gr * IN + c4 * 4]);
        float* d = &sx[row * STRIDE + c4 * 4];
        d[0] = v.x; d[1] = v.y; d[2] = v.z; d[3] = v.w;
    }
    __syncthreads();

    int w = t >> 6, lane = t & 63;
    int s = __builtin_amdgcn_readfirstlane(w % SPLIT);
    int grp = __builtin_amdgcn_readfirstlane(w / SPLIT);
    int r = grp * 64 + lane;
    long n = base + r;

    float acc[16];
#pragma unroll
    for (int j = 0; j < 16; ++j) acc[j] = 0.f;

    const float* Ws = W + s * 16;
#pragma unroll 8
    for (int k = 0; k < IN; ++k) {
        float xv = sx[r * STRIDE + k];
        const float* Wr = Ws + k * OUT;
#pragma unroll
        for (int j = 0; j < 16; ++j) acc[j] = fmaf(xv, Wr[j], acc[j]);
    }

    if (n < N_NODES) {
        unsigned u[8];
#pragma unroll
        for (int k = 0; k < 8; ++k)
            u[k] = f2bf(acc[2 * k]) | (f2bf(acc[2 * k + 1]) << 16);
        uint4* dst = reinterpret_cast<uint4*>(&h[n * OUT + s * 16]);
        dst[0] = make_uint4(u[0], u[1], u[2], u[3]);
        dst[1] = make_uint4(u[4], u[5], u[6], u[7]);
    }

    float ps = 0.f, pd = 0.f;
#pragma unroll
    for (int j = 0; j < 16; ++j) {
        ps = fmaf(acc[j], asrc[s * 16 + j], ps);
        pd = fmaf(acc[j], adst[s * 16 + j], pd);
    }
    if (HEADS == SPLIT) {
        if (n < N_NODES) {
            als[n * HEADS + s] = ps;
            ald[n * HEADS + s] = pd;
        }
    } else {
        __syncthreads();
        sx[r * 2 + s] = ps;
        sx[NPB * 2 + r * 2 + s] = pd;
        __syncthreads();
        if (t < NPB) {
            long nn = base + t;
            if (nn < N_NODES) {
                als[nn] = sx[t * 2] + sx[t * 2 + 1];
                ald[nn] = sx[NPB * 2 + t * 2] + sx[NPB * 2 + t * 2 + 1];
            }
        }
    }
}

// XCD-aligned node mapping for agg: XCD k (blockIdx&7) processes dst range k.
static __device__ __forceinline__ int agg_node(int blk, int wid) {
    return (blk & 7) * PART_SZ + (blk >> 3) * 4 + wid;
}

// ---------------- aggregation, H=4 C=16, bf16 payload ----------------
// Round-17 pathology: register full-depth prefetch was silently re-serialized by the
// compiler (VGPR_Count=28 — can't hold 6x uint4; MachineSink sank each load into its
// use block -> depth-1 again, 55.9 us flat). Fix: issue the gathers as
// global_load_lds (per-lane GLOBAL gather addr is legal; LDS dest = uniform base +
// lane*size). No register destination -> nothing to sink; all nit h-gathers + als
// gathers are in flight simultaneously (up to 12 misses/wave vs 1). One vmcnt(0) +
// sched_barrier, then compute out of LDS.
__global__ __launch_bounds__(256) void agg_h4(const int* __restrict__ cnt, const int* __restrict__ srcs,
                                              const unsigned short* __restrict__ h, const float* __restrict__ als,
                                              const float* __restrict__ ald, const float* __restrict__ bias,
                                              float* __restrict__ g, int do_relu) {
    __shared__ uint4 hbuf[4][KD4][64];   // 24 KB
    __shared__ float abuf[4][KD4][64];   // 6 KB
    const uint4* hrow = reinterpret_cast<const uint4*>(h);   // 8 uint4 per 64-ch row
    int wid = threadIdx.x >> 6, lane = threadIdx.x & 63;
    int n = agg_node(blockIdx.x, wid);
    if (n >= N_NODES) return;
    int q = lane >> 3, cc = lane & 7;
    int hd = cc >> 1;
    float ad = ald[n * 4 + hd];
    int deg = cnt[n]; if (deg > CAP) deg = CAP;   // deg >= 1 (self-loop), wave-uniform
    int sl = srcs[n * CAP + (lane < deg ? lane : deg - 1)];  // whole bucket, one coalesced load
    int nit = (deg + 7) >> 3;                     // 1..6, wave-uniform

#pragma unroll
    for (int t = 0; t < KD4; ++t) {
        if (t < nit) {                            // wave-uniform guard
            int e = t * 8 + q;
            int s = __shfl(sl, e < deg ? e : deg - 1);
            __builtin_amdgcn_global_load_lds(
                (const __attribute__((address_space(1))) void*)&als[s * 4 + hd],
                (__attribute__((address_space(3))) void*)&abuf[wid][t][0], 4, 0, 0);
            __builtin_amdgcn_global_load_lds(
                (const __attribute__((address_space(1))) void*)&hrow[(long)s * 8 + cc],
                (__attribute__((address_space(3))) void*)&hbuf[wid][t][0], 16, 0, 0);
        }
    }
    asm volatile("s_waitcnt vmcnt(0)" ::: "memory");
    __builtin_amdgcn_sched_barrier(0);

    float a0 = 0.f, a1 = 0.f, a2 = 0.f, a3 = 0.f, a4 = 0.f, a5 = 0.f, a6 = 0.f, a7 = 0.f;
    float den = 0.f;
#pragma unroll
    for (int t = 0; t < KD4; ++t) {
        if (t < nit) {
            float al = abuf[wid][t][lane];
            uint4 hv = hbuf[wid][t][lane];
            float w = (t * 8 + q) < deg ? __expf(lrelu(al + ad)) : 0.f;
            den += w;
            a0 = fmaf(w, bf_lo(hv.x), a0);
            a1 = fmaf(w, bf_hi(hv.x), a1);
            a2 = fmaf(w, bf_lo(hv.y), a2);
            a3 = fmaf(w, bf_hi(hv.y), a3);
            a4 = fmaf(w, bf_lo(hv.z), a4);
            a5 = fmaf(w, bf_hi(hv.z), a5);
            a6 = fmaf(w, bf_lo(hv.w), a6);
            a7 = fmaf(w, bf_hi(hv.w), a7);
        }
    }

#pragma unroll
    for (int d = 8; d <= 32; d <<= 1) {
        a0 += __shfl_xor(a0, d); a1 += __shfl_xor(a1, d);
        a2 += __shfl_xor(a2, d); a3 += __shfl_xor(a3, d);
        a4 += __shfl_xor(a4, d); a5 += __shfl_xor(a5, d);
        a6 += __shfl_xor(a6, d); a7 += __shfl_xor(a7, d);
        den += __shfl_xor(den, d);
    }
    if (q == 0) {
        float4 b0 = *reinterpret_cast<const float4*>(&bias[cc * 8]);
        float4 b1 = *reinterpret_cast<const float4*>(&bias[cc * 8 + 4]);
        float inv = 1.f / den;
        float4 o0, o1;
        o0.x = fmaf(a0, inv, b0.x); o0.y = fmaf(a1, inv, b0.y);
        o0.z = fmaf(a2, inv, b0.z); o0.w = fmaf(a3, inv, b0.w);
        o1.x = fmaf(a4, inv, b1.x); o1.y = fmaf(a5, inv, b1.y);
        o1.z = fmaf(a6, inv, b1.z); o1.w = fmaf(a7, inv, b1.w);
        if (do_relu) {
            o0.x = fmaxf(o0.x, 0.f); o0.y = fmaxf(o0.y, 0.f);
            o0.z = fmaxf(o0.z, 0.f); o0.w = fmaxf(o0.w, 0.f);
            o1.x = fmaxf(o1.x, 0.f); o1.y = fmaxf(o1.y, 0.f);
            o1.z = fmaxf(o1.z, 0.f); o1.w = fmaxf(o1.w, 0.f);
        }
        *reinterpret_cast<float4*>(&g[(long)n * 64 + cc * 8]) = o0;
        *reinterpret_cast<float4*>(&g[(long)n * 64 + cc * 8 + 4]) = o1;
    }
}

// ---------------- aggregation, H=1 C=32, bf16 payload ----------------
// Same LDS-DMA full-depth gather; nit <= 3 (16 edges per group, 4 lanes/row).
__global__ __launch_bounds__(256) void agg_h1(const int* __restrict__ cnt, const int* __restrict__ srcs,
                                              const unsigned short* __restrict__ h3, const float* __restrict__ als,
                                              const float* __restrict__ ald, const float* __restrict__ bias,
                                              float* __restrict__ out) {
    __shared__ uint4 hbuf[4][KD1][64];   // 12 KB
    __shared__ float abuf[4][KD1][64];   // 3 KB
    const uint4* hrow = reinterpret_cast<const uint4*>(h3);  // 4 uint4 per 32-ch row
    int wid = threadIdx.x >> 6, lane = threadIdx.x & 63;
    int n = agg_node(blockIdx.x, wid);
    if (n >= N_NODES) return;
    int q = lane >> 2, cc = lane & 3;
    float ad = ald[n];
    int deg = cnt[n]; if (deg > CAP) deg = CAP;
    int sl = srcs[n * CAP + (lane < deg ? lane : deg - 1)];
    int nit = (deg + 15) >> 4;                    // 1..3, wave-uniform

#pragma unroll
    for (int t = 0; t < KD1; ++t) {
        if (t < nit) {
            int e = t * 16 + q;
            int s = __shfl(sl, e < deg ? e : deg - 1);
            __builtin_amdgcn_global_load_lds(
                (const __attribute__((address_space(1))) void*)&als[s],
                (__attribute__((address_space(3))) void*)&abuf[wid][t][0], 4, 0, 0);
            __builtin_amdgcn_global_load_lds(
                (const __attribute__((address_space(1))) void*)&hrow[(long)s * 4 + cc],
                (__attribute__((address_space(3))) void*)&hbuf[wid][t][0], 16, 0, 0);
        }
    }
    asm volatile("s_waitcnt vmcnt(0)" ::: "memory");
    __builtin_amdgcn_sched_barrier(0);

    float a0 = 0.f, a1 = 0.f, a2 = 0.f, a3 = 0.f, a4 = 0.f, a5 = 0.f, a6 = 0.f, a7 = 0.f;
    float den = 0.f;
#pragma unroll
    for (int t = 0; t < KD1; ++t) {
        if (t < nit) {
            float al = abuf[wid][t][lane];
            uint4 hv = hbuf[wid][t][lane];
            float w = (t * 16 + q) < deg ? __expf(lrelu(al + ad)) : 0.f;
            den += w;
            a0 = fmaf(w, bf_lo(hv.x), a0);
            a1 = fmaf(w, bf_hi(hv.x), a1);
            a2 = fmaf(w, bf_lo(hv.y), a2);
            a3 = fmaf(w, bf_hi(hv.y), a3);
            a4 = fmaf(w, bf_lo(hv.z), a4);
            a5 = fmaf(w, bf_hi(hv.z), a5);
            a6 = fmaf(w, bf_lo(hv.w), a6);
            a7 = fmaf(w, bf_hi(hv.w), a7);
        }
    }

#pragma unroll
    for (int d = 4; d <= 32; d <<= 1) {
        a0 += __shfl_xor(a0, d); a1 += __shfl_xor(a1, d);
        a2 += __shfl_xor(a2, d); a3 += __shfl_xor(a3, d);
        a4 += __shfl_xor(a4, d); a5 += __shfl_xor(a5, d);
        a6 += __shfl_xor(a6, d); a7 += __shfl_xor(a7, d);
        den += __shfl_xor(den, d);
    }
    if (q == 0) {
        float4 b0 = *reinterpret_cast<const float4*>(&bias[cc * 8]);
        float4 b1 = *reinterpret_cast<const float4*>(&bias[cc * 8 + 4]);
        float inv = 1.f / den;
        float4 o0, o1;
        o0.x = fmaf(a0, inv, b0.x); o0.y = fmaf(a1, inv, b0.y);
        o0.z = fmaf(a2, inv, b0.z); o0.w = fmaf(a3, inv, b0.w);
        o1.x = fmaf(a4, inv, b1.x); o1.y = fmaf(a5, inv, b1.y);
        o1.z = fmaf(a6, inv, b1.z); o1.w = fmaf(a7, inv, b1.w);
        *reinterpret_cast<float4*>(&out[(long)n * 32 + cc * 8]) = o0;
        *reinterpret_cast<float4*>(&out[(long)n * 32 + cc * 8 + 4]) = o1;
    }
}

extern "C" void kernel_launch(void* const* d_in, const int* in_sizes, int n_in,
                              void* d_out, int out_size, void* d_ws, size_t ws_size,
                              hipStream_t stream) {
    (void)in_sizes; (void)n_in; (void)out_size; (void)ws_size;
    const float* x   = (const float*)d_in[0];
    const int*   ei  = (const int*)d_in[1];
    const float* W1  = (const float*)d_in[2];
    const float* as1 = (const float*)d_in[3];
    const float* ad1 = (const float*)d_in[4];
    const float* b1  = (const float*)d_in[5];
    const float* W2  = (const float*)d_in[6];
    const float* as2 = (const float*)d_in[7];
    const float* ad2 = (const float*)d_in[8];
    const float* b2  = (const float*)d_in[9];
    const float* W3  = (const float*)d_in[10];
    const float* as3 = (const float*)d_in[11];
    const float* ad3 = (const float*)d_in[12];
    const float* b3  = (const float*)d_in[13];
    float* out = (float*)d_out;

    char* w = (char*)d_ws;
    auto alloc = [&](size_t bytes) {
        void* p = (void*)w;
        w += (bytes + 255) & ~(size_t)255;
        return p;
    };
    int*            cnt   = (int*)alloc((size_t)N_NODES * 4);
    int*            tails = (int*)alloc((size_t)1024 * 4);            // 8 stripes x 128-int pad
    int*            srcs  = (int*)alloc((size_t)N_NODES * CAP * 4);   // 19.2 MB
    unsigned short* h     = (unsigned short*)alloc((size_t)N_NODES * 64 * 2);  // bf16, 12.8 MB
    float*          g     = (float*)alloc((size_t)N_NODES * 64 * 4);  // 25.6 MB
    float*          als   = (float*)alloc((size_t)N_NODES * 4 * 4);
    float*          ald   = (float*)alloc((size_t)N_NODES * 4 * 4);
    // staging (12.85 MB) aliases g: consumed by bucket_fill before agg_h4 first writes g.
    unsigned*       stage = (unsigned*)g;

    hipMemsetAsync(tails, 0, (size_t)1024 * 4, stream);   // cnt memset no longer needed

    int g64  = (N_NODES + 63) / 64;    // 1563
    int g128 = (N_NODES + 127) / 128;  // 782
    int gAgg = ((N_NODES + 3) / 4 + 7) & ~7;   // 25000 -> mult of 8
    int gBuild = (N_EDGES + EPB - 1) / EPB;    // 782 (self-loops not staged)

    bucket_build<<<gBuild, 256, 0, stream>>>(ei, tails, stage);
    bucket_fill<<<NBIN, 1024, 0, stream>>>(tails, stage, cnt, srcs);

    // layer 1: x[100000,128] @ W1[128,64], H=4
    gemm_al<128, 64, 4, 64><<<g64, 256, 0, stream>>>(x, W1, as1, ad1, h, als, ald);
    agg_h4<<<gAgg, 256, 0, stream>>>(cnt, srcs, h, als, ald, b1, g, 1);
    // layer 2: g[100000,64] @ W2[64,64], H=4
    gemm_al<64, 64, 4, 64><<<g64, 256, 0, stream>>>(g, W2, as2, ad2, h, als, ald);
    agg_h4<<<gAgg, 256, 0, stream>>>(cnt, srcs, h, als, ald, b2, g, 1);
    // layer 3: g[100000,64] @ W3[64,32], H=1 -> d_out
    gemm_al<64, 32, 1, 128><<<g128, 256, 0, stream>>>(g, W3, as3, ad3, h, als, ald);
    agg_h1<<<gAgg, 256, 0, stream>>>(cnt, srcs, h, als, ald, b3, out);
}

// Round 8
// 347.840 us; speedup vs baseline: 1.1739x; 1.1739x over previous
//
#include <hip/hip_runtime.h>

#define N_NODES 100000
#define N_EDGES 1600000
#define NPART   8
#define PART_SZ (N_NODES / NPART)   // 12500 (agg node mapping)
#define CAP 48                      // bucket capacity; degree ~ Poisson(16), P(>=48) ~ 1e-9
#define BSH  10                     // nodes per fill bin = 1024 (node-exclusive block ownership)
#define NBIN 98                     // ceil(100000 / 1024)
#define SCAP2 4096                  // per-(bin,stripe) staging cap: mean 2048, sigma 45 -> +45 sigma
#define SSH2 12                     // log2(SCAP2)
#define EPB  2048                   // edges per build block

static __device__ __forceinline__ float lrelu(float z) { return z > 0.f ? z : 0.2f * z; }
static __device__ __forceinline__ int imin(int a, int b) { return a < b ? a : b; }

// bf16 round-to-nearest-even pack / unpack (values are finite, no NaN handling)
static __device__ __forceinline__ unsigned f2bf(float f) {
    unsigned u = __float_as_uint(f);
    u += 0x7fffu + ((u >> 16) & 1u);
    return u >> 16;
}
static __device__ __forceinline__ float bf_lo(unsigned v) { return __uint_as_float(v << 16); }
static __device__ __forceinline__ float bf_hi(unsigned v) { return __uint_as_float(v & 0xffff0000u); }

// ---------------- phase A: single-pass edge binning at 1024-node granularity ----------------
// (round-15: validated — bucket phase now ~25 us total, fill write-amp gone)
__global__ __launch_bounds__(256) void bucket_build(const int* __restrict__ ei, int* __restrict__ tails,
                                                    unsigned* __restrict__ stage) {
    __shared__ int lcnt[NBIN];
    __shared__ int lbase[NBIN];
    int tid = threadIdx.x;
    if (tid < NBIN) lcnt[tid] = 0;
    __syncthreads();

    int stripe = blockIdx.x & 7;
    int e0 = blockIdx.x * EPB;
    int binv[EPB / 256];
    int slotv[EPB / 256];
    unsigned vv[EPB / 256];
#pragma unroll
    for (int k = 0; k < EPB / 256; ++k) {
        int t = e0 + k * 256 + tid;
        binv[k] = -1;
        if (t < N_EDGES) {
            int d = __builtin_nontemporal_load(ei + N_EDGES + t);
            int s = __builtin_nontemporal_load(ei + t);
            int b = d >> BSH;
            vv[k] = ((unsigned)(d & ((1 << BSH) - 1)) << 17) | (unsigned)s;  // dloc 10b | src 17b
            slotv[k] = atomicAdd(&lcnt[b], 1);
            binv[k] = b;
        }
    }
    __syncthreads();

    if (tid < NBIN) lbase[tid] = atomicAdd(&tails[stripe * 128 + tid], lcnt[tid]);
    __syncthreads();

#pragma unroll
    for (int k = 0; k < EPB / 256; ++k) {
        if (binv[k] >= 0) {
            int pos = lbase[binv[k]] + slotv[k];
            if (pos < SCAP2)
                stage[((((unsigned)binv[k] << 3) | (unsigned)stripe) << SSH2) + (unsigned)pos] = vv[k];
        }
    }
}

// ---------------- phase B: node-exclusive bucket assembly, LDS counters only ----------------
__global__ __launch_bounds__(1024) void bucket_fill(const int* __restrict__ tails, const unsigned* __restrict__ stage,
                                                    int* __restrict__ cnt, int* __restrict__ srcs) {
    __shared__ int lc[1 << BSH];
    int tid = threadIdx.x;
    int bin = blockIdx.x;
    int base = bin << BSH;
    int nn = N_NODES - base; if (nn > (1 << BSH)) nn = 1 << BSH;
    if (tid < nn) {
        lc[tid] = 1;                           // self-loop occupies slot 0
        srcs[(base + tid) * CAP] = base + tid;
    }
    __syncthreads();

    for (int st = 0; st < 8; ++st) {
        int len = tails[st * 128 + bin];
        if (len > SCAP2) len = SCAP2;
        const unsigned* sl = stage + ((((unsigned)bin << 3) | (unsigned)st) << SSH2);
        for (int i = tid; i < len; i += 1024) {
            unsigned v = __builtin_nontemporal_load(sl + i);
            int dloc = (int)(v >> 17);
            int s = (int)(v & 0x1FFFFu);
            int slot = atomicAdd(&lc[dloc], 1);
            if (slot < CAP) srcs[(base + dloc) * CAP + slot] = s;
        }
    }
    __syncthreads();
    if (tid < nn) cnt[base + tid] = lc[tid];   // agg clamps deg > CAP
}

// ---------------- fused GEMM + attention logits (wave-sliced, scalar W path) ----------------
template <int IN, int OUT, int HEADS, int NPB>
__global__ __launch_bounds__(256) void gemm_al(const float* __restrict__ x, const float* __restrict__ W,
                                               const float* __restrict__ asrc, const float* __restrict__ adst,
                                               unsigned short* __restrict__ h, float* __restrict__ als,
                                               float* __restrict__ ald) {
    constexpr int SPLIT = OUT / 16;
    constexpr int STRIDE = IN + 1;
    constexpr int F4PT = NPB * (IN / 4) / 256;
    __shared__ float sx[NPB * STRIDE];
    int t = threadIdx.x;
    long base = (long)blockIdx.x * NPB;

#pragma unroll
    for (int p = 0; p < F4PT; ++p) {
        int e = p * 256 + t;
        int row = e / (IN / 4);
        int c4 = e % (IN / 4);
        long gr = base + row;
        if (gr >= N_NODES) gr = N_NODES - 1;
        float4 v = *reinterpret_cast<const float4*>(&x[gr * IN + c4 * 4]);
        float* d = &sx[row * STRIDE + c4 * 4];
        d[0] = v.x; d[1] = v.y; d[2] = v.z; d[3] = v.w;
    }
    __syncthreads();

    int w = t >> 6, lane = t & 63;
    int s = __builtin_amdgcn_readfirstlane(w % SPLIT);
    int grp = __builtin_amdgcn_readfirstlane(w / SPLIT);
    int r = grp * 64 + lane;
    long n = base + r;

    float acc[16];
#pragma unroll
    for (int j = 0; j < 16; ++j) acc[j] = 0.f;

    const float* Ws = W + s * 16;
#pragma unroll 8
    for (int k = 0; k < IN; ++k) {
        float xv = sx[r * STRIDE + k];
        const float* Wr = Ws + k * OUT;
#pragma unroll
        for (int j = 0; j < 16; ++j) acc[j] = fmaf(xv, Wr[j], acc[j]);
    }

    if (n < N_NODES) {
        unsigned u[8];
#pragma unroll
        for (int k = 0; k < 8; ++k)
            u[k] = f2bf(acc[2 * k]) | (f2bf(acc[2 * k + 1]) << 16);
        uint4* dst = reinterpret_cast<uint4*>(&h[n * OUT + s * 16]);
        dst[0] = make_uint4(u[0], u[1], u[2], u[3]);
        dst[1] = make_uint4(u[4], u[5], u[6], u[7]);
    }

    float ps = 0.f, pd = 0.f;
#pragma unroll
    for (int j = 0; j < 16; ++j) {
        ps = fmaf(acc[j], asrc[s * 16 + j], ps);
        pd = fmaf(acc[j], adst[s * 16 + j], pd);
    }
    if (HEADS == SPLIT) {
        if (n < N_NODES) {
            als[n * HEADS + s] = ps;
            ald[n * HEADS + s] = pd;
        }
    } else {
        __syncthreads();
        sx[r * 2 + s] = ps;
        sx[NPB * 2 + r * 2 + s] = pd;
        __syncthreads();
        if (t < NPB) {
            long nn = base + t;
            if (nn < N_NODES) {
                als[nn] = sx[t * 2] + sx[t * 2 + 1];
                ald[nn] = sx[NPB * 2 + t * 2] + sx[NPB * 2 + t * 2 + 1];
            }
        }
    }
}

// XCD-aligned node mapping for agg: XCD k (blockIdx&7) processes dst range k.
static __device__ __forceinline__ int agg_node(int blk, int wid) {
    return (blk & 7) * PART_SZ + (blk >> 3) * 4 + wid;
}

// ---------------- aggregation, H=4 C=16, bf16 payload, uint4 lanes ----------------
// Round-18: round-6's guarded register prefetch was re-serialized by MachineSink
// (VGPR=28 proved loads sank into guarded use blocks); round-7's LDS-DMA traded
// occupancy for MLP and lost (45% occ, full vmcnt(0) drain). Fix: BRANCHLESS
// fixed-depth-4 prefetch — clamped indices make all addresses valid, loads are
// straight-line (no successor block to sink into), sched_barrier(0) fences the
// load cluster from the compute, masked w kills clamp duplicates. deg>32 tail
// (P~1e-4) runs a wave-uniform 1-deep loop.
__global__ __launch_bounds__(256, 8) void agg_h4(const int* __restrict__ cnt, const int* __restrict__ srcs,
                                                 const unsigned short* __restrict__ h, const float* __restrict__ als,
                                                 const float* __restrict__ ald, const float* __restrict__ bias,
                                                 float* __restrict__ g, int do_relu) {
    const uint4* hrow = reinterpret_cast<const uint4*>(h);   // 8 uint4 per 64-ch row
    int wid = threadIdx.x >> 6, lane = threadIdx.x & 63;
    int n = agg_node(blockIdx.x, wid);
    if (n >= N_NODES) return;
    int q = lane >> 3, cc = lane & 7;
    int hd = cc >> 1;
    float ad = ald[n * 4 + hd];
    int deg = cnt[n]; if (deg > CAP) deg = CAP;   // deg >= 1 (self-loop), wave-uniform
    int dm1 = deg - 1;
    int sl = srcs[n * CAP + imin(lane, dm1)];     // whole bucket, one coalesced load

    // addresses (shfl chain), then 8 independent loads, all before the fence
    int s0 = __shfl(sl, imin(0 * 8 + q, dm1));
    int s1 = __shfl(sl, imin(1 * 8 + q, dm1));
    int s2 = __shfl(sl, imin(2 * 8 + q, dm1));
    int s3 = __shfl(sl, imin(3 * 8 + q, dm1));
    float al0 = als[s0 * 4 + hd];
    float al1 = als[s1 * 4 + hd];
    float al2 = als[s2 * 4 + hd];
    float al3 = als[s3 * 4 + hd];
    uint4 hv0 = hrow[(long)s0 * 8 + cc];
    uint4 hv1 = hrow[(long)s1 * 8 + cc];
    uint4 hv2 = hrow[(long)s2 * 8 + cc];
    uint4 hv3 = hrow[(long)s3 * 8 + cc];
    __builtin_amdgcn_sched_barrier(0);

    float a0 = 0.f, a1 = 0.f, a2 = 0.f, a3 = 0.f, a4 = 0.f, a5 = 0.f, a6 = 0.f, a7 = 0.f;
    float den = 0.f;
#define ACCUM(AL, HV, T)                                             \
    {                                                                \
        float w = ((T) * 8 + q) < deg ? __expf(lrelu((AL) + ad)) : 0.f; \
        den += w;                                                    \
        a0 = fmaf(w, bf_lo((HV).x), a0); a1 = fmaf(w, bf_hi((HV).x), a1); \
        a2 = fmaf(w, bf_lo((HV).y), a2); a3 = fmaf(w, bf_hi((HV).y), a3); \
        a4 = fmaf(w, bf_lo((HV).z), a4); a5 = fmaf(w, bf_hi((HV).z), a5); \
        a6 = fmaf(w, bf_lo((HV).w), a6); a7 = fmaf(w, bf_hi((HV).w), a7); \
    }
    ACCUM(al0, hv0, 0)
    ACCUM(al1, hv1, 1)
    ACCUM(al2, hv2, 2)
    ACCUM(al3, hv3, 3)

    if (__builtin_expect(deg > 32, 0)) {          // wave-uniform rare tail
        for (int e = 32; e < deg; e += 8) {
            int ee = e + q;
            int s = __shfl(sl, imin(ee, dm1));
            float al = als[s * 4 + hd];
            uint4 hv = hrow[(long)s * 8 + cc];
            float w = ee < deg ? __expf(lrelu(al + ad)) : 0.f;
            den += w;
            a0 = fmaf(w, bf_lo(hv.x), a0); a1 = fmaf(w, bf_hi(hv.x), a1);
            a2 = fmaf(w, bf_lo(hv.y), a2); a3 = fmaf(w, bf_hi(hv.y), a3);
            a4 = fmaf(w, bf_lo(hv.z), a4); a5 = fmaf(w, bf_hi(hv.z), a5);
            a6 = fmaf(w, bf_lo(hv.w), a6); a7 = fmaf(w, bf_hi(hv.w), a7);
        }
    }
#undef ACCUM

#pragma unroll
    for (int d = 8; d <= 32; d <<= 1) {
        a0 += __shfl_xor(a0, d); a1 += __shfl_xor(a1, d);
        a2 += __shfl_xor(a2, d); a3 += __shfl_xor(a3, d);
        a4 += __shfl_xor(a4, d); a5 += __shfl_xor(a5, d);
        a6 += __shfl_xor(a6, d); a7 += __shfl_xor(a7, d);
        den += __shfl_xor(den, d);
    }
    if (q == 0) {
        float4 b0 = *reinterpret_cast<const float4*>(&bias[cc * 8]);
        float4 b1 = *reinterpret_cast<const float4*>(&bias[cc * 8 + 4]);
        float inv = 1.f / den;
        float4 o0, o1;
        o0.x = fmaf(a0, inv, b0.x); o0.y = fmaf(a1, inv, b0.y);
        o0.z = fmaf(a2, inv, b0.z); o0.w = fmaf(a3, inv, b0.w);
        o1.x = fmaf(a4, inv, b1.x); o1.y = fmaf(a5, inv, b1.y);
        o1.z = fmaf(a6, inv, b1.z); o1.w = fmaf(a7, inv, b1.w);
        if (do_relu) {
            o0.x = fmaxf(o0.x, 0.f); o0.y = fmaxf(o0.y, 0.f);
            o0.z = fmaxf(o0.z, 0.f); o0.w = fmaxf(o0.w, 0.f);
            o1.x = fmaxf(o1.x, 0.f); o1.y = fmaxf(o1.y, 0.f);
            o1.z = fmaxf(o1.z, 0.f); o1.w = fmaxf(o1.w, 0.f);
        }
        *reinterpret_cast<float4*>(&g[(long)n * 64 + cc * 8]) = o0;
        *reinterpret_cast<float4*>(&g[(long)n * 64 + cc * 8 + 4]) = o1;
    }
}

// ---------------- aggregation, H=1 C=32, bf16 payload, uint4 lanes ----------------
// Branchless fixed-depth-2 prefetch (16-edge groups, covers deg<=32) + rare tail.
__global__ __launch_bounds__(256, 8) void agg_h1(const int* __restrict__ cnt, const int* __restrict__ srcs,
                                                 const unsigned short* __restrict__ h3, const float* __restrict__ als,
                                                 const float* __restrict__ ald, const float* __restrict__ bias,
                                                 float* __restrict__ out) {
    const uint4* hrow = reinterpret_cast<const uint4*>(h3);  // 4 uint4 per 32-ch row
    int wid = threadIdx.x >> 6, lane = threadIdx.x & 63;
    int n = agg_node(blockIdx.x, wid);
    if (n >= N_NODES) return;
    int q = lane >> 2, cc = lane & 3;
    float ad = ald[n];
    int deg = cnt[n]; if (deg > CAP) deg = CAP;
    int dm1 = deg - 1;
    int sl = srcs[n * CAP + imin(lane, dm1)];

    int s0 = __shfl(sl, imin(0 * 16 + q, dm1));
    int s1 = __shfl(sl, imin(1 * 16 + q, dm1));
    float al0 = als[s0];
    float al1 = als[s1];
    uint4 hv0 = hrow[(long)s0 * 4 + cc];
    uint4 hv1 = hrow[(long)s1 * 4 + cc];
    __builtin_amdgcn_sched_barrier(0);

    float a0 = 0.f, a1 = 0.f, a2 = 0.f, a3 = 0.f, a4 = 0.f, a5 = 0.f, a6 = 0.f, a7 = 0.f;
    float den = 0.f;
#define ACCUM1(AL, HV, T)                                            \
    {                                                                \
        float w = ((T) * 16 + q) < deg ? __expf(lrelu((AL) + ad)) : 0.f; \
        den += w;                                                    \
        a0 = fmaf(w, bf_lo((HV).x), a0); a1 = fmaf(w, bf_hi((HV).x), a1); \
        a2 = fmaf(w, bf_lo((HV).y), a2); a3 = fmaf(w, bf_hi((HV).y), a3); \
        a4 = fmaf(w, bf_lo((HV).z), a4); a5 = fmaf(w, bf_hi((HV).z), a5); \
        a6 = fmaf(w, bf_lo((HV).w), a6); a7 = fmaf(w, bf_hi((HV).w), a7); \
    }
    ACCUM1(al0, hv0, 0)
    ACCUM1(al1, hv1, 1)

    if (__builtin_expect(deg > 32, 0)) {          // wave-uniform rare tail
        for (int e = 32; e < deg; e += 16) {
            int ee = e + q;
            int s = __shfl(sl, imin(ee, dm1));
            float al = als[s];
            uint4 hv = hrow[(long)s * 4 + cc];
            float w = ee < deg ? __expf(lrelu(al + ad)) : 0.f;
            den += w;
            a0 = fmaf(w, bf_lo(hv.x), a0); a1 = fmaf(w, bf_hi(hv.x), a1);
            a2 = fmaf(w, bf_lo(hv.y), a2); a3 = fmaf(w, bf_hi(hv.y), a3);
            a4 = fmaf(w, bf_lo(hv.z), a4); a5 = fmaf(w, bf_hi(hv.z), a5);
            a6 = fmaf(w, bf_lo(hv.w), a6); a7 = fmaf(w, bf_hi(hv.w), a7);
        }
    }
#undef ACCUM1

#pragma unroll
    for (int d = 4; d <= 32; d <<= 1) {
        a0 += __shfl_xor(a0, d); a1 += __shfl_xor(a1, d);
        a2 += __shfl_xor(a2, d); a3 += __shfl_xor(a3, d);
        a4 += __shfl_xor(a4, d); a5 += __shfl_xor(a5, d);
        a6 += __shfl_xor(a6, d); a7 += __shfl_xor(a7, d);
        den += __shfl_xor(den, d);
    }
    if (q == 0) {
        float4 b0 = *reinterpret_cast<const float4*>(&bias[cc * 8]);
        float4 b1 = *reinterpret_cast<const float4*>(&bias[cc * 8 + 4]);
        float inv = 1.f / den;
        float4 o0, o1;
        o0.x = fmaf(a0, inv, b0.x); o0.y = fmaf(a1, inv, b0.y);
        o0.z = fmaf(a2, inv, b0.z); o0.w = fmaf(a3, inv, b0.w);
        o1.x = fmaf(a4, inv, b1.x); o1.y = fmaf(a5, inv, b1.y);
        o1.z = fmaf(a6, inv, b1.z); o1.w = fmaf(a7, inv, b1.w);
        *reinterpret_cast<float4*>(&out[(long)n * 32 + cc * 8]) = o0;
        *reinterpret_cast<float4*>(&out[(long)n * 32 + cc * 8 + 4]) = o1;
    }
}

extern "C" void kernel_launch(void* const* d_in, const int* in_sizes, int n_in,
                              void* d_out, int out_size, void* d_ws, size_t ws_size,
                              hipStream_t stream) {
    (void)in_sizes; (void)n_in; (void)out_size; (void)ws_size;
    const float* x   = (const float*)d_in[0];
    const int*   ei  = (const int*)d_in[1];
    const float* W1  = (const float*)d_in[2];
    const float* as1 = (const float*)d_in[3];
    const float* ad1 = (const float*)d_in[4];
    const float* b1  = (const float*)d_in[5];
    const float* W2  = (const float*)d_in[6];
    const float* as2 = (const float*)d_in[7];
    const float* ad2 = (const float*)d_in[8];
    const float* b2  = (const float*)d_in[9];
    const float* W3  = (const float*)d_in[10];
    const float* as3 = (const float*)d_in[11];
    const float* ad3 = (const float*)d_in[12];
    const float* b3  = (const float*)d_in[13];
    float* out = (float*)d_out;

    char* w = (char*)d_ws;
    auto alloc = [&](size_t bytes) {
        void* p = (void*)w;
        w += (bytes + 255) & ~(size_t)255;
        return p;
    };
    int*            cnt   = (int*)alloc((size_t)N_NODES * 4);
    int*            tails = (int*)alloc((size_t)1024 * 4);            // 8 stripes x 128-int pad
    int*            srcs  = (int*)alloc((size_t)N_NODES * CAP * 4);   // 19.2 MB
    unsigned short* h     = (unsigned short*)alloc((size_t)N_NODES * 64 * 2);  // bf16, 12.8 MB
    float*          g     = (float*)alloc((size_t)N_NODES * 64 * 4);  // 25.6 MB
    float*          als   = (float*)alloc((size_t)N_NODES * 4 * 4);
    float*          ald   = (float*)alloc((size_t)N_NODES * 4 * 4);
    // staging (12.85 MB) aliases g: consumed by bucket_fill before agg_h4 first writes g.
    unsigned*       stage = (unsigned*)g;

    hipMemsetAsync(tails, 0, (size_t)1024 * 4, stream);   // cnt memset no longer needed

    int g64  = (N_NODES + 63) / 64;    // 1563
    int g128 = (N_NODES + 127) / 128;  // 782
    int gAgg = ((N_NODES + 3) / 4 + 7) & ~7;   // 25000 -> mult of 8
    int gBuild = (N_EDGES + EPB - 1) / EPB;    // 782 (self-loops not staged)

    bucket_build<<<gBuild, 256, 0, stream>>>(ei, tails, stage);
    bucket_fill<<<NBIN, 1024, 0, stream>>>(tails, stage, cnt, srcs);

    // layer 1: x[100000,128] @ W1[128,64], H=4
    gemm_al<128, 64, 4, 64><<<g64, 256, 0, stream>>>(x, W1, as1, ad1, h, als, ald);
    agg_h4<<<gAgg, 256, 0, stream>>>(cnt, srcs, h, als, ald, b1, g, 1);
    // layer 2: g[100000,64] @ W2[64,64], H=4
    gemm_al<64, 64, 4, 64><<<g64, 256, 0, stream>>>(g, W2, as2, ad2, h, als, ald);
    agg_h4<<<gAgg, 256, 0, stream>>>(cnt, srcs, h, als, ald, b2, g, 1);
    // layer 3: g[100000,64] @ W3[64,32], H=1 -> d_out
    gemm_al<64, 32, 1, 128><<<g128, 256, 0, stream>>>(g, W3, as3, ad3, h, als, ald);
    agg_h1<<<gAgg, 256, 0, stream>>>(cnt, srcs, h, als, ald, b3, out);
}